// Round 5
// baseline (230.076 us; speedup 1.0000x reference)
//
#include <hip/hip_runtime.h>

// Dynamic conv2d: B=32, C=128, H=W=56, O=128, K(banks)=2, 3x3 pad1 stride1.
// 3-kernel pipeline:
//   convert_k: x fp32 NCHW -> xh bf16 NHWC + per-(b,h) c-rowsums + zero page
//   wagg2_k:   partial->pooled -> MLP/softmax (redundant per block) -> Wb bf16 + aggb
//   conv4_k:   512-thr MFMA shift-GEMM, A+B via global_load_lds, dbuf, raw barriers

#define B_ 32
#define C_ 128
#define O_ 128
#define SP_ 3136   // 56*56

typedef __bf16  bf16x8 __attribute__((ext_vector_type(8)));
typedef short   short8 __attribute__((ext_vector_type(8)));
typedef float   f32x4  __attribute__((ext_vector_type(4)));

__device__ __forceinline__ short f2bf(float f) {
  unsigned u = __float_as_uint(f);
  u += 0x7fffu + ((u >> 16) & 1u);
  return (short)(u >> 16);
}
__device__ __forceinline__ float bf2f(short s) {
  return __uint_as_float(((unsigned)(unsigned short)s) << 16);
}

#define GLOAD_LDS16(gp, lp)                                                     \
  __builtin_amdgcn_global_load_lds(                                             \
      (const __attribute__((address_space(1))) unsigned int*)(gp),              \
      (__attribute__((address_space(3))) unsigned int*)(lp), 16, 0, 0)

// ws byte offsets
#define WS_PARTIAL_F 0           // 32*56*128 floats (917504 B)
#define WS_AGGB_F    229440     // 4096 floats (bytes 917760..934143)
#define WS_ZERO_B    934144     // 1024 B zero page
#define WS_WB_B      935168     // 9437184 B
#define WS_XH_B      10372352   // 25690112 B

// ---------------- convert: x fp32 NCHW -> xh bf16 NHWC + rowsums + zero page
__global__ __launch_bounds__(256) void convert_k(const float* __restrict__ x,
                                                 char* __restrict__ wsbase) {
  const int h = blockIdx.x, b = blockIdx.y;
  const int tid = threadIdx.x;
  __shared__ short lc[C_ * 57];
  __shared__ float red[256];
  if (h == 0 && b == 0)                       // zero halo page (1 KB)
    ((int*)(wsbase + WS_ZERO_B))[tid] = 0;
  const float* xp = x + (size_t)b * C_ * SP_ + h * 56;
#pragma unroll
  for (int q = 0; q < 7; ++q) {
    int i = q * 256 + tid;                    // c*14 + w4chunk
    int c = i / 14, w4 = (i - c * 14) * 4;
    float4 v = *reinterpret_cast<const float4*>(xp + (size_t)c * SP_ + w4);
    lc[c * 57 + w4 + 0] = f2bf(v.x);
    lc[c * 57 + w4 + 1] = f2bf(v.y);
    lc[c * 57 + w4 + 2] = f2bf(v.z);
    lc[c * 57 + w4 + 3] = f2bf(v.w);
  }
  __syncthreads();
  {                                           // parallel rowsum: (c, half) per thread
    const int c = tid & 127, half = tid >> 7;
    float s = 0.f;
#pragma unroll
    for (int w = half * 28; w < half * 28 + 28; ++w) s += bf2f(lc[c * 57 + w]);
    red[tid] = s;
  }
  __syncthreads();
  if (tid < C_) {
    float* partial = (float*)wsbase + WS_PARTIAL_F;
    partial[((size_t)b * 56 + h) * C_ + tid] = red[tid] + red[tid + 128];
  }
  short* xo = (short*)(wsbase + WS_XH_B) + ((size_t)b * 56 + h) * 56 * C_;
  for (int u = tid; u < 896; u += 256) {      // 56 w x 16 c-parts
    int w = u >> 4, cp = (u & 15) * 8;
    short8 v;
#pragma unroll
    for (int k = 0; k < 8; ++k) v[k] = lc[(cp + k) * 57 + w];
    *reinterpret_cast<short8*>(xo + w * C_ + cp) = v;
  }
}

// ---------------- wagg2: pooled+MLP (redundant per block) + weight agg + aggb
// grid 256 = 32 b x 8 o-groups, 256 threads
__global__ __launch_bounds__(256) void wagg2_k(const float* __restrict__ w0,
                                               const float* __restrict__ w1,
                                               const float* __restrict__ fc1,
                                               const float* __restrict__ fc2,
                                               const float* __restrict__ cbias,
                                               const float* __restrict__ dbias,
                                               char* __restrict__ wsbase) {
  const int b = blockIdx.x >> 3, og = blockIdx.x & 7;
  const int o0 = og * 16;
  const int tid = threadIdx.x;
  const float* partial = (const float*)wsbase + WS_PARTIAL_F;
  __shared__ float red[256];
  __shared__ float pooled_s[C_];
  __shared__ float hid[32];
  __shared__ float lg[2];
  __shared__ float at[2];
  __shared__ short wl[9 * 16 * C_];           // [ij][o-o0][c]

  {                                           // partial -> pooled (this b)
    const int c = tid & 127, half = tid >> 7;
    float s = 0.f;
    for (int hh = half * 28; hh < half * 28 + 28; ++hh)
      s += partial[((size_t)b * 56 + hh) * C_ + c];
    red[tid] = s;
  }
  __syncthreads();
  if (tid < C_) pooled_s[tid] = (red[tid] + red[tid + 128]) * (1.f / 3136.f);
  __syncthreads();
  {                                           // fc1: 32 hd x 8 parts of 16 c
    const int hd = tid >> 3, part = tid & 7;
    const float4* fa = reinterpret_cast<const float4*>(fc1 + hd * C_ + part * 16);
    const float4* pa = reinterpret_cast<const float4*>(pooled_s + part * 16);
    float s = 0.f;
#pragma unroll
    for (int i = 0; i < 4; ++i) {
      float4 f = fa[i], p = pa[i];
      s += f.x * p.x + f.y * p.y + f.z * p.z + f.w * p.w;
    }
    red[tid] = s;
  }
  __syncthreads();
  if (tid < 32) {
    float v = 0.f;
#pragma unroll
    for (int j = 0; j < 8; ++j) v += red[tid * 8 + j];
    hid[tid] = fmaxf(v, 0.f);
  }
  __syncthreads();
  if (tid < 64) red[tid] = hid[tid & 31] * fc2[tid];
  __syncthreads();
  if (tid < 2) {
    float l = 0.f;
#pragma unroll
    for (int hh = 0; hh < 32; ++hh) l += red[tid * 32 + hh];
    lg[tid] = l * (1.f / 31.f);
  }
  __syncthreads();
  if (tid == 0) {
    float m = fmaxf(lg[0], lg[1]);
    float e0 = __expf(lg[0] - m), e1 = __expf(lg[1] - m);
    float inv = 1.f / (e0 + e1);
    at[0] = e0 * inv; at[1] = e1 * inv;
  }
  __syncthreads();
  const float a0 = at[0], a1 = at[1];
  if (og == 0 && tid < C_) {
    float* aggb = (float*)wsbase + WS_AGGB_F;
    aggb[b * O_ + tid] = a0 * cbias[tid] + a1 * dbias[tid];
  }
#pragma unroll
  for (int it = 0; it < 8; ++it) {
    int r = it * 256 + tid;                   // (o-o0)*128 + c
    int o = o0 + (r >> 7), c = r & 127;
    size_t base = ((size_t)o * C_ + c) * 9;
#pragma unroll
    for (int j = 0; j < 9; ++j) {
      float v = a0 * w0[base + j] + a1 * w1[base + j];
      wl[j * 2048 + r] = f2bf(v);
    }
  }
  __syncthreads();
  short* Wb = (short*)(wsbase + WS_WB_B);
#pragma unroll
  for (int it = 0; it < 9; ++it) {
    int u = it * 256 + tid;
    int ij = u >> 8, v = (u & 255) * 8;
    *reinterpret_cast<short8*>(Wb + (((size_t)b * 9 + ij) * O_ + o0) * C_ + v) =
        *reinterpret_cast<const short8*>(&wl[ij * 2048 + v]);
  }
}

// ---------------- conv4: 512 threads = 8 waves (4M x 2N) ----------------
// flat grid 448 (XCD-bijective), out 128o x 224pos per block.
// 36 k-steps (4 c-chunks x 9 taps), K=32. B: 348pos x 32c swizzled 16B granules,
// dbuf 2x22272. A: 128o x 32c swizzled granules, dbuf 2x8192.
#define BUNITS 1392
#define BBUF 22272
#define AOFF 44544
#define ABUF 8192
__global__ __launch_bounds__(512, 4) void conv4_k(const char* __restrict__ wsbase,
                                                  float* __restrict__ out) {
  const int flat = blockIdx.x;
  const int swz = (flat & 7) * 56 + (flat >> 3);
  const int b = swz / 14, ht = swz - b * 14;
  const int h0 = ht * 4;
  const int tid = threadIdx.x;
  const int lane = tid & 63, wv = tid >> 6;
  const int obase = (wv >> 1) * 32;           // 4 M-waves
  const int nbase = (wv & 1) * 112;           // 2 N-waves
  const int l15 = lane & 15, g = lane >> 4;
  const float* aggb = (const float*)wsbase + WS_AGGB_F;

  __shared__ __align__(16) char xs[AOFF + 2 * ABUF];   // 60928 B

  // B staging geometry: unit u = it*512 + tid (u < 1392)
  const char* gsrcB[3];
  bool gact[3];
#pragma unroll
  for (int it = 0; it < 3; ++it) {
    int u = it * 512 + tid;
    gact[it] = (u < BUNITS);
    int uu = gact[it] ? u : 0;
    int pos = uu >> 2;
    int q = ((uu & 3) - (uu >> 4)) & 3;       // inverse granule swizzle
    int r = pos / 58, wc = pos - r * 58;
    int h = h0 - 1 + r, w = wc - 1;
    bool val = (unsigned)h < 56u && (unsigned)w < 56u;
    gsrcB[it] = wsbase + (val ? (WS_XH_B + 2 * ((((b * 56 + h) * 56 + w) << 7) + q * 8))
                              : WS_ZERO_B);
  }
  // A staging geometry: unit u = tid (512 units = 128o x 4 granules)
  const char* gsrcA;
  {
    int o = tid >> 2;
    int q = ((tid & 3) - (tid >> 4)) & 3;
    gsrcA = wsbase + WS_WB_B + 2 * ((size_t)b * 147456 + o * C_ + q * 8);
  }
  // A read offsets (per m)
  int aoffR[2];
#pragma unroll
  for (int m = 0; m < 2; ++m) {
    int o = obase + m * 16 + l15;
    aoffR[m] = (o << 6) + (((g + (o >> 2)) & 3) << 4);
  }
  // B read positions (center tap)
  int ptile[7];
#pragma unroll
  for (int n = 0; n < 7; ++n) {
    int p = nbase + n * 16 + l15;
    int hl = p / 56, wl = p - hl * 56;
    ptile[n] = (hl + 1) * 58 + (wl + 1);
  }

  f32x4 acc[2][7];
#pragma unroll
  for (int m = 0; m < 2; ++m)
#pragma unroll
    for (int n = 0; n < 7; ++n) acc[m][n] = f32x4{0.f, 0.f, 0.f, 0.f};

  // prolog: stage B(chunk0) + A(step0)
#pragma unroll
  for (int it = 0; it < 3; ++it)
    if (gact[it]) GLOAD_LDS16(gsrcB[it], xs + it * 8192 + wv * 1024);
  GLOAD_LDS16(gsrcA, xs + AOFF + wv * 1024);
  asm volatile("s_waitcnt vmcnt(0)" ::: "memory");
  __builtin_amdgcn_s_barrier();

#pragma unroll
  for (int cc = 0; cc < 4; ++cc) {
#pragma unroll
    for (int ij = 0; ij < 9; ++ij) {
      const int s = cc * 9 + ij;
      const int apar = s & 1, bpar = cc & 1;
      if (s < 35) {                            // A stage for step s+1
        const int s2 = s + 1, cc2 = s2 / 9, ij2 = s2 - cc2 * 9;
        GLOAD_LDS16(gsrcA + 2 * (ij2 * 16384 + cc2 * 32),
                    xs + AOFF + ((s2 & 1) ? ABUF : 0) + wv * 1024);
      }
      if (ij == 0 && cc < 3) {                 // B stage for chunk cc+1
#pragma unroll
        for (int it = 0; it < 3; ++it)
          if (gact[it])
            GLOAD_LDS16(gsrcB[it] + (cc + 1) * 64,
                        xs + (bpar ? 0 : BBUF) + it * 8192 + wv * 1024);
      }
      // compute step s
      const char* abuf = xs + AOFF + (apar ? ABUF : 0);
      const char* bbuf = xs + (bpar ? BBUF : 0);
      bf16x8 af[2];
#pragma unroll
      for (int m = 0; m < 2; ++m)
        af[m] = *reinterpret_cast<const bf16x8*>(abuf + aoffR[m]);
      const int sh = (ij / 3 - 1) * 58 + (ij % 3 - 1);
      __builtin_amdgcn_s_setprio(1);
#pragma unroll
      for (int n = 0; n < 7; ++n) {
        int pp = ptile[n] + sh;
        int off = (pp << 6) + ((((pp >> 2) + g) & 3) << 4);
        bf16x8 bfr = *reinterpret_cast<const bf16x8*>(bbuf + off);
#pragma unroll
        for (int m = 0; m < 2; ++m)
          acc[m][n] = __builtin_amdgcn_mfma_f32_16x16x32_bf16(af[m], bfr, acc[m][n], 0, 0, 0);
      }
      __builtin_amdgcn_s_setprio(0);
      if (s < 35) {
        asm volatile("s_waitcnt vmcnt(0)" ::: "memory");
        __builtin_amdgcn_s_barrier();
      }
    }
  }

  // epilogue
  const int r4 = g * 4;
#pragma unroll
  for (int m = 0; m < 2; ++m) {
    float bias[4];
#pragma unroll
    for (int j = 0; j < 4; ++j) bias[j] = aggb[b * O_ + obase + m * 16 + r4 + j];
#pragma unroll
    for (int n = 0; n < 7; ++n) {
      int p = nbase + n * 16 + l15;
      int h = h0 + p / 56, w = p % 56;
#pragma unroll
      for (int j = 0; j < 4; ++j) {
        int o = obase + m * 16 + r4 + j;
        out[((size_t)(b * O_ + o) * 56 + h) * 56 + w] = acc[m][n][j] + bias[j];
      }
    }
  }
}

extern "C" void kernel_launch(void* const* d_in, const int* in_sizes, int n_in,
                              void* d_out, int out_size, void* d_ws, size_t ws_size,
                              hipStream_t stream) {
  const float* x   = (const float*)d_in[0];
  const float* cw  = (const float*)d_in[1];
  const float* cb  = (const float*)d_in[2];
  const float* dw  = (const float*)d_in[3];
  const float* db  = (const float*)d_in[4];
  const float* fc1 = (const float*)d_in[5];
  const float* fc2 = (const float*)d_in[6];
  float* out = (float*)d_out;
  char* wsb  = (char*)d_ws;

  convert_k<<<dim3(56, B_), 256, 0, stream>>>(x, wsb);
  wagg2_k<<<256, 256, 0, stream>>>(cw, dw, fc1, fc2, cb, db, wsb);
  conv4_k<<<448, 512, 0, stream>>>(wsb, out);
}

// Round 6
// 157.364 us; speedup vs baseline: 1.4621x; 1.4621x over previous
//
#include <hip/hip_runtime.h>

// Dynamic conv2d: B=32, C=128, H=W=56, O=128, K(banks)=2, 3x3 pad1 stride1.
// convert_k: x fp32 NCHW -> xh bf16 NHWC + rowsums + zero page
// wagg2_k:   partial->pooled -> MLP/softmax (redundant per block) -> Wb bf16 + aggb
// conv5_k:   896 blocks x 256 thr (4 waves 4Mx1N), all-LDS k-step pipeline,
//            A+B via global_load_lds, dbuf, raw barriers, no reg caps.

#define B_ 32
#define C_ 128
#define O_ 128
#define SP_ 3136   // 56*56

typedef __bf16  bf16x8 __attribute__((ext_vector_type(8)));
typedef short   short8 __attribute__((ext_vector_type(8)));
typedef float   f32x4  __attribute__((ext_vector_type(4)));

__device__ __forceinline__ short f2bf(float f) {
  unsigned u = __float_as_uint(f);
  u += 0x7fffu + ((u >> 16) & 1u);
  return (short)(u >> 16);
}
__device__ __forceinline__ float bf2f(short s) {
  return __uint_as_float(((unsigned)(unsigned short)s) << 16);
}

#define GLOAD_LDS16(gp, lp)                                                     \
  __builtin_amdgcn_global_load_lds(                                             \
      (const __attribute__((address_space(1))) unsigned int*)(gp),              \
      (__attribute__((address_space(3))) unsigned int*)(lp), 16, 0, 0)

// ws byte offsets
#define WS_PARTIAL_F 0           // 32*56*128 floats (917504 B)
#define WS_AGGB_F    229440     // 4096 floats
#define WS_ZERO_B    934144     // 1024 B zero page
#define WS_WB_B      935168     // 9437184 B
#define WS_XH_B      10372352   // 25690112 B

// ---------------- convert: x fp32 NCHW -> xh bf16 NHWC + rowsums + zero page
__global__ __launch_bounds__(256) void convert_k(const float* __restrict__ x,
                                                 char* __restrict__ wsbase) {
  const int h = blockIdx.x, b = blockIdx.y;
  const int tid = threadIdx.x;
  __shared__ short lc[C_ * 57];
  __shared__ float red[256];
  if (h == 0 && b == 0)
    ((int*)(wsbase + WS_ZERO_B))[tid] = 0;
  const float* xp = x + (size_t)b * C_ * SP_ + h * 56;
#pragma unroll
  for (int q = 0; q < 7; ++q) {
    int i = q * 256 + tid;                    // c*14 + w4chunk
    int c = i / 14, w4 = (i - c * 14) * 4;
    float4 v = *reinterpret_cast<const float4*>(xp + (size_t)c * SP_ + w4);
    lc[c * 57 + w4 + 0] = f2bf(v.x);
    lc[c * 57 + w4 + 1] = f2bf(v.y);
    lc[c * 57 + w4 + 2] = f2bf(v.z);
    lc[c * 57 + w4 + 3] = f2bf(v.w);
  }
  __syncthreads();
  {
    const int c = tid & 127, half = tid >> 7;
    float s = 0.f;
#pragma unroll
    for (int w = half * 28; w < half * 28 + 28; ++w) s += bf2f(lc[c * 57 + w]);
    red[tid] = s;
  }
  __syncthreads();
  if (tid < C_) {
    float* partial = (float*)wsbase + WS_PARTIAL_F;
    partial[((size_t)b * 56 + h) * C_ + tid] = red[tid] + red[tid + 128];
  }
  short* xo = (short*)(wsbase + WS_XH_B) + ((size_t)b * 56 + h) * 56 * C_;
  for (int u = tid; u < 896; u += 256) {
    int w = u >> 4, cp = (u & 15) * 8;
    short8 v;
#pragma unroll
    for (int k = 0; k < 8; ++k) v[k] = lc[(cp + k) * 57 + w];
    *reinterpret_cast<short8*>(xo + w * C_ + cp) = v;
  }
}

// ---------------- wagg2: pooled+MLP (redundant per block) + weight agg + aggb
__global__ __launch_bounds__(256) void wagg2_k(const float* __restrict__ w0,
                                               const float* __restrict__ w1,
                                               const float* __restrict__ fc1,
                                               const float* __restrict__ fc2,
                                               const float* __restrict__ cbias,
                                               const float* __restrict__ dbias,
                                               char* __restrict__ wsbase) {
  const int b = blockIdx.x >> 3, og = blockIdx.x & 7;
  const int o0 = og * 16;
  const int tid = threadIdx.x;
  const float* partial = (const float*)wsbase + WS_PARTIAL_F;
  __shared__ float red[256];
  __shared__ float pooled_s[C_];
  __shared__ float hid[32];
  __shared__ float lg[2];
  __shared__ float at[2];
  __shared__ short wl[9 * 16 * C_];

  {
    const int c = tid & 127, half = tid >> 7;
    float s = 0.f;
    for (int hh = half * 28; hh < half * 28 + 28; ++hh)
      s += partial[((size_t)b * 56 + hh) * C_ + c];
    red[tid] = s;
  }
  __syncthreads();
  if (tid < C_) pooled_s[tid] = (red[tid] + red[tid + 128]) * (1.f / 3136.f);
  __syncthreads();
  {
    const int hd = tid >> 3, part = tid & 7;
    const float4* fa = reinterpret_cast<const float4*>(fc1 + hd * C_ + part * 16);
    const float4* pa = reinterpret_cast<const float4*>(pooled_s + part * 16);
    float s = 0.f;
#pragma unroll
    for (int i = 0; i < 4; ++i) {
      float4 f = fa[i], p = pa[i];
      s += f.x * p.x + f.y * p.y + f.z * p.z + f.w * p.w;
    }
    red[tid] = s;
  }
  __syncthreads();
  if (tid < 32) {
    float v = 0.f;
#pragma unroll
    for (int j = 0; j < 8; ++j) v += red[tid * 8 + j];
    hid[tid] = fmaxf(v, 0.f);
  }
  __syncthreads();
  if (tid < 64) red[tid] = hid[tid & 31] * fc2[tid];
  __syncthreads();
  if (tid < 2) {
    float l = 0.f;
#pragma unroll
    for (int hh = 0; hh < 32; ++hh) l += red[tid * 32 + hh];
    lg[tid] = l * (1.f / 31.f);
  }
  __syncthreads();
  if (tid == 0) {
    float m = fmaxf(lg[0], lg[1]);
    float e0 = __expf(lg[0] - m), e1 = __expf(lg[1] - m);
    float inv = 1.f / (e0 + e1);
    at[0] = e0 * inv; at[1] = e1 * inv;
  }
  __syncthreads();
  const float a0 = at[0], a1 = at[1];
  if (og == 0 && tid < C_) {
    float* aggb = (float*)wsbase + WS_AGGB_F;
    aggb[b * O_ + tid] = a0 * cbias[tid] + a1 * dbias[tid];
  }
#pragma unroll
  for (int it = 0; it < 8; ++it) {
    int r = it * 256 + tid;
    int o = o0 + (r >> 7), c = r & 127;
    size_t base = ((size_t)o * C_ + c) * 9;
#pragma unroll
    for (int j = 0; j < 9; ++j) {
      float v = a0 * w0[base + j] + a1 * w1[base + j];
      wl[j * 2048 + r] = f2bf(v);
    }
  }
  __syncthreads();
  short* Wb = (short*)(wsbase + WS_WB_B);
#pragma unroll
  for (int it = 0; it < 9; ++it) {
    int u = it * 256 + tid;
    int ij = u >> 8, v = (u & 255) * 8;
    *reinterpret_cast<short8*>(Wb + (((size_t)b * 9 + ij) * O_ + o0) * C_ + v) =
        *reinterpret_cast<const short8*>(&wl[ij * 2048 + v]);
  }
}

// ---------------- conv5: 896 blocks (32 b x 28 two-row tiles), 256 thr ----------
// 4 waves 4Mx1N: wave wv owns o in [wv*32, wv*32+32), all 112 positions.
// 36 k-steps (4 c-chunks x 9 taps), K=32. B: 232 pos x 32c swizzled 16B
// granules, dbuf 2x14848. A: 128o x 32c swizzled, dbuf 2x8192. LDS 46080 B.
#define BUNITS5 928           // 232*4
#define BBUF5 14848
#define AOFF5 29696
#define ABUF5 8192
__global__ __launch_bounds__(256) void conv5_k(const char* __restrict__ wsbase,
                                               float* __restrict__ out) {
  const int flat = blockIdx.x;                  // 896
  const int swz = (flat & 7) * 112 + (flat >> 3);  // XCD-bijective
  const int b = swz / 28, ht = swz - b * 28;
  const int h0 = ht * 2;
  const int tid = threadIdx.x;
  const int lane = tid & 63, wv = tid >> 6;
  const int obase = wv * 32;
  const int l15 = lane & 15, g = lane >> 4;
  const float* aggb = (const float*)wsbase + WS_AGGB_F;

  __shared__ __align__(16) char xs[AOFF5 + 2 * ABUF5];   // 46080 B

  // B staging geometry: unit u = it*256 + tid (u < 928)
  const char* gsrcB[4];
  bool gact[4];
#pragma unroll
  for (int it = 0; it < 4; ++it) {
    int u = it * 256 + tid;
    gact[it] = (u < BUNITS5);
    int uu = gact[it] ? u : 0;
    int pos = uu >> 2;
    int q = ((uu & 3) - (uu >> 4)) & 3;       // inverse granule swizzle
    int r = pos / 58, wc = pos - r * 58;
    int h = h0 - 1 + r, w = wc - 1;
    bool val = (unsigned)h < 56u && (unsigned)w < 56u;
    gsrcB[it] = wsbase + (val ? (WS_XH_B + 2 * ((((b * 56 + h) * 56 + w) << 7) + q * 8))
                              : WS_ZERO_B);
  }
  // A staging geometry: units u = tid, tid+256 (512 units = 128o x 4 granules)
  const char* gsrcA[2];
#pragma unroll
  for (int it = 0; it < 2; ++it) {
    int u = it * 256 + tid;
    int o = u >> 2;
    int q = ((u & 3) - (u >> 4)) & 3;
    gsrcA[it] = wsbase + WS_WB_B + 2 * ((size_t)b * 147456 + o * C_ + q * 8);
  }
  // A read offsets (per m)
  int aoffR[2];
#pragma unroll
  for (int m = 0; m < 2; ++m) {
    int o = obase + m * 16 + l15;
    aoffR[m] = (o << 6) + (((g + (o >> 2)) & 3) << 4);
  }
  // B read positions (center tap); p in 0..111
  int ptile[7];
#pragma unroll
  for (int n = 0; n < 7; ++n) {
    int p = n * 16 + l15;
    int hl = p / 56, wl = p - hl * 56;
    ptile[n] = (hl + 1) * 58 + (wl + 1);
  }

  f32x4 acc[2][7];
#pragma unroll
  for (int m = 0; m < 2; ++m)
#pragma unroll
    for (int n = 0; n < 7; ++n) acc[m][n] = f32x4{0.f, 0.f, 0.f, 0.f};

  // prolog: stage B(chunk0) + A(step0)
#pragma unroll
  for (int it = 0; it < 4; ++it)
    if (gact[it]) GLOAD_LDS16(gsrcB[it], xs + it * 4096 + wv * 1024);
#pragma unroll
  for (int it = 0; it < 2; ++it)
    GLOAD_LDS16(gsrcA[it], xs + AOFF5 + it * 4096 + wv * 1024);
  asm volatile("s_waitcnt vmcnt(0)" ::: "memory");
  __builtin_amdgcn_s_barrier();

#pragma unroll
  for (int cc = 0; cc < 4; ++cc) {
#pragma unroll
    for (int ij = 0; ij < 9; ++ij) {
      const int s = cc * 9 + ij;
      const int apar = s & 1, bpar = cc & 1;
      if (s < 35) {                            // A stage for step s+1
        const int s2 = s + 1, cc2 = s2 / 9, ij2 = s2 - cc2 * 9;
        const int adelta = 2 * (ij2 * 16384 + cc2 * 32);
#pragma unroll
        for (int it = 0; it < 2; ++it)
          GLOAD_LDS16(gsrcA[it] + adelta,
                      xs + AOFF5 + ((s2 & 1) ? ABUF5 : 0) + it * 4096 + wv * 1024);
      }
      if (ij == 0 && cc < 3) {                 // B stage for chunk cc+1
#pragma unroll
        for (int it = 0; it < 4; ++it)
          if (gact[it])
            GLOAD_LDS16(gsrcB[it] + (cc + 1) * 64,
                        xs + (bpar ? 0 : BBUF5) + it * 4096 + wv * 1024);
      }
      // compute step s
      const char* abuf = xs + AOFF5 + (apar ? ABUF5 : 0);
      const char* bbuf = xs + (bpar ? BBUF5 : 0);
      bf16x8 af[2];
#pragma unroll
      for (int m = 0; m < 2; ++m)
        af[m] = *reinterpret_cast<const bf16x8*>(abuf + aoffR[m]);
      const int sh = (ij / 3 - 1) * 58 + (ij % 3 - 1);
      __builtin_amdgcn_s_setprio(1);
#pragma unroll
      for (int n = 0; n < 7; ++n) {
        int pp = ptile[n] + sh;
        int off = (pp << 6) + ((((pp >> 2) + g) & 3) << 4);
        bf16x8 bfr = *reinterpret_cast<const bf16x8*>(bbuf + off);
#pragma unroll
        for (int m = 0; m < 2; ++m)
          acc[m][n] = __builtin_amdgcn_mfma_f32_16x16x32_bf16(af[m], bfr, acc[m][n], 0, 0, 0);
      }
      __builtin_amdgcn_s_setprio(0);
      if (s < 35) {
        asm volatile("s_waitcnt vmcnt(0)" ::: "memory");
        __builtin_amdgcn_s_barrier();
      }
    }
  }

  // epilogue
  const int r4 = g * 4;
#pragma unroll
  for (int m = 0; m < 2; ++m) {
    float bias[4];
#pragma unroll
    for (int j = 0; j < 4; ++j) bias[j] = aggb[b * O_ + obase + m * 16 + r4 + j];
#pragma unroll
    for (int n = 0; n < 7; ++n) {
      int p = n * 16 + l15;
      int h = h0 + p / 56, w = p % 56;
#pragma unroll
      for (int j = 0; j < 4; ++j) {
        int o = obase + m * 16 + r4 + j;
        out[((size_t)(b * O_ + o) * 56 + h) * 56 + w] = acc[m][n][j] + bias[j];
      }
    }
  }
}

extern "C" void kernel_launch(void* const* d_in, const int* in_sizes, int n_in,
                              void* d_out, int out_size, void* d_ws, size_t ws_size,
                              hipStream_t stream) {
  const float* x   = (const float*)d_in[0];
  const float* cw  = (const float*)d_in[1];
  const float* cb  = (const float*)d_in[2];
  const float* dw  = (const float*)d_in[3];
  const float* db  = (const float*)d_in[4];
  const float* fc1 = (const float*)d_in[5];
  const float* fc2 = (const float*)d_in[6];
  float* out = (float*)d_out;
  char* wsb  = (char*)d_ws;

  convert_k<<<dim3(56, B_), 256, 0, stream>>>(x, wsb);
  wagg2_k<<<256, 256, 0, stream>>>(cw, dw, fc1, fc2, cb, db, wsb);
  conv5_k<<<896, 256, 0, stream>>>(wsb, out);
}